// Round 11
// baseline (126.068 us; speedup 1.0000x reference)
//
#include <hip/hip_runtime.h>
#include <hip/hip_cooperative_groups.h>
#include <math.h>

// MultiheadSelfAttention2D: C=256, AC=64, HEADS=16, HEAD_DIM=4, L=4096.
// Taylor-linearized attention (R5): exp(q.k) ~= T5 on [-1,1], exact rank-126
// monomial factorization:
//   S_f = (1/a!) sum_m k_m^a ;  Z_j = sum_f q_j^a S_f
//   M[f][d] = (1/a!) sum_j q_j^a V[d,j]/Z_j ;  out[d,i] = sum_f k_i^a M[f][d]
//
// R11: cooperative mega done right. R7's coop failed on occupancy (256
// blocks = 4 waves/CU); R9/R10 proved the phase shapes healthy at >=8
// waves/CU. Here: 1024 blocks x 256 thr, __launch_bounds__(256,4) => 4
// blocks/CU co-resident (16 waves/CU), max phase LDS 39.75 KB. 5 grid.syncs
// replace 5 dispatch boundaries (~8-10us each). Host occupancy query picks
// coop vs 6-dispatch fallback (same phase bodies).

namespace cg = cooperative_groups;

constexpr int SL = 4096;
constexpr int NF = 126;

__device__ __forceinline__ float invfact(int e) {
    return e < 2 ? 1.f : e == 2 ? 0.5f : e == 3 ? (1.f / 6.f)
         : e == 4 ? (1.f / 24.f) : (1.f / 120.f);
}
__device__ __forceinline__ void f2abcd(int f, int& A, int& B, int& C, int& D) {
    for (int a = 0; a <= 5; ++a)
        for (int b = 0; b <= 5 - a; ++b)
            for (int c = 0; c <= 5 - a - b; ++c)
                for (int d = 0; d <= 5 - a - b - c; ++d)
                    if (f-- == 0) { A = a; B = b; C = c; D = d; return; }
}

#define FOR_MONOMIALS(BODY)                         \
    {                                               \
        int f = 0;                                  \
        _Pragma("unroll")                           \
        for (int a = 0; a <= 5; ++a)                \
        _Pragma("unroll")                           \
        for (int b = 0; b <= 5 - a; ++b)            \
        _Pragma("unroll")                           \
        for (int c = 0; c <= 5 - a - b; ++c)        \
        _Pragma("unroll")                           \
        for (int d = 0; d <= 5 - a - b - c; ++d) {  \
            BODY;                                   \
            ++f;                                    \
        }                                           \
    }

#define BUILD_POWERS(q)                                   \
    float p0[6], p1[6], p2[6], p3[6];                     \
    p0[0] = p1[0] = p2[0] = p3[0] = 1.f;                  \
    _Pragma("unroll")                                     \
    for (int t_ = 1; t_ < 6; ++t_) {                      \
        p0[t_] = p0[t_ - 1] * (q).x; p1[t_] = p1[t_ - 1] * (q).y; \
        p2[t_] = p2[t_ - 1] * (q).z; p3[t_] = p3[t_ - 1] * (q).w; }

// ============================ phase bodies =================================

// P1: QKV projection + L2-norm. Workers: bid < 768 (64 lt x 12 rb). No LDS.
__device__ __forceinline__ void phase_qkv(int bid, int tid,
    const float* __restrict__ X,
    const float* __restrict__ Wq, const float* __restrict__ bq,
    const float* __restrict__ Wk, const float* __restrict__ bk,
    const float* __restrict__ Wv, const float* __restrict__ bv,
    float* __restrict__ Qn, float* __restrict__ Kn, float* __restrict__ V4f)
{
    if (bid >= 768) return;
    const int lane = tid & 63;
    const int wv   = __builtin_amdgcn_readfirstlane(tid >> 6);
    const int lt   = bid & 63;
    const int rb   = bid >> 6;                 // 0..11
    const int type = rb >> 2;                  // 0=Q 1=K 2=V
    const int rit  = (rb & 3) * 16 + wv * 4;
    const int l    = lt * 64 + lane;

    const float* W = type == 0 ? Wq : type == 1 ? Wk : Wv;
    const float* B = type == 0 ? bq : type == 1 ? bk : bv;
    const float* w0 = W + (rit + 0) * 256;
    const float* w1 = W + (rit + 1) * 256;
    const float* w2 = W + (rit + 2) * 256;
    const float* w3 = W + (rit + 3) * 256;

    float y0 = B[rit + 0], y1 = B[rit + 1], y2 = B[rit + 2], y3 = B[rit + 3];
    const float* Xl = X + l;
    #pragma unroll 8
    for (int c = 0; c < 256; ++c) {
        float x = Xl[c * SL];
        y0 = fmaf(w0[c], x, y0);
        y1 = fmaf(w1[c], x, y1);
        y2 = fmaf(w2[c], x, y2);
        y3 = fmaf(w3[c], x, y3);
    }
    if (type < 2) {
        float n = sqrtf(y0*y0 + y1*y1 + y2*y2 + y3*y3);
        float inv = 1.f / fmaxf(n, 1e-12f);
        y0 *= inv; y1 *= inv; y2 *= inv; y3 *= inv;
    }
    const int h = rit >> 2;
    float* base = type == 0 ? Qn : type == 1 ? Kn : V4f;
    ((float4*)base)[h * SL + l] = make_float4(y0, y1, y2, y3);
}

// P2: Sp[jc][h][f] = (1/a!) sum over j-chunk(1024) of k^a. Workers: 1024.
template <int FC>
__device__ __forceinline__ void psi_accum(int h, int jc, int tid,
        const float* __restrict__ Kn, float acc[8])
{
    for (int u = 0; u < 4; ++u) {
        int j = jc * 1024 + u * 256 + tid;
        float4 k = ((const float4*)Kn)[h * SL + j];
        BUILD_POWERS(k)
        FOR_MONOMIALS({
            if (f >= FC * 8 && f < FC * 8 + 8)
                acc[f - FC * 8] += (p0[a] * p1[b]) * (p2[c] * p3[d]);
        })
    }
}

__device__ __forceinline__ void phase_ssum(int bid, int tid, float* lds,
    const float* __restrict__ Kn, float* __restrict__ Sp)
{
    const int fc = bid & 15, h = (bid >> 4) & 15, jc = bid >> 8;
    float acc[8];
    #pragma unroll
    for (int k = 0; k < 8; ++k) acc[k] = 0.f;
    switch (fc) {
        case 0:  psi_accum<0 >(h, jc, tid, Kn, acc); break;
        case 1:  psi_accum<1 >(h, jc, tid, Kn, acc); break;
        case 2:  psi_accum<2 >(h, jc, tid, Kn, acc); break;
        case 3:  psi_accum<3 >(h, jc, tid, Kn, acc); break;
        case 4:  psi_accum<4 >(h, jc, tid, Kn, acc); break;
        case 5:  psi_accum<5 >(h, jc, tid, Kn, acc); break;
        case 6:  psi_accum<6 >(h, jc, tid, Kn, acc); break;
        case 7:  psi_accum<7 >(h, jc, tid, Kn, acc); break;
        case 8:  psi_accum<8 >(h, jc, tid, Kn, acc); break;
        case 9:  psi_accum<9 >(h, jc, tid, Kn, acc); break;
        case 10: psi_accum<10>(h, jc, tid, Kn, acc); break;
        case 11: psi_accum<11>(h, jc, tid, Kn, acc); break;
        case 12: psi_accum<12>(h, jc, tid, Kn, acc); break;
        case 13: psi_accum<13>(h, jc, tid, Kn, acc); break;
        case 14: psi_accum<14>(h, jc, tid, Kn, acc); break;
        default: psi_accum<15>(h, jc, tid, Kn, acc); break;
    }
    #pragma unroll
    for (int off = 32; off; off >>= 1)
        #pragma unroll
        for (int k = 0; k < 8; ++k) acc[k] += __shfl_down(acc[k], off);
    float* red = lds;                          // [4][8]
    const int lane = tid & 63, wv = tid >> 6;
    if (lane == 0) {
        #pragma unroll
        for (int k = 0; k < 8; ++k) red[wv * 8 + k] = acc[k];
    }
    __syncthreads();
    if (tid < 8) {
        int f = fc * 8 + tid;
        if (f < NF) {
            float s = (red[tid] + red[8 + tid]) + (red[16 + tid] + red[24 + tid]);
            int A, B, C, D; f2abcd(f, A, B, C, D);
            Sp[(jc * 16 + h) * 128 + f] =
                s * ((invfact(A) * invfact(B)) * (invfact(C) * invfact(D)));
        }
    }
    __syncthreads();                           // lds reused by next phase user
}

// P3: Z_j + Vz, 1024 workers (64 jt x 16 h), features split across 4 waves.
template <int W>
__device__ __forceinline__ float z_part(const float p0[6], const float p1[6],
        const float p2[6], const float p3[6], const float* Sf)
{
    float z = 0.f;
    FOR_MONOMIALS({
        if (f >= W * 32 && f < W * 32 + 32)
            z = fmaf((p0[a] * p1[b]) * (p2[c] * p3[d]), Sf[f], z);
    })
    return z;
}

__device__ __forceinline__ void phase_zvz(int bid, int tid, float* lds,
    const float* __restrict__ Qn, const float* __restrict__ Sp,
    const float* __restrict__ V4f, float* __restrict__ Vz)
{
    float* SfL = lds;                          // [128]
    float* ZQ  = lds + 128;                    // [4][64]
    const int h = bid & 15, jt = bid >> 4;     // jt 0..63
    if (tid < 128) {
        float s = 0.f;
        #pragma unroll
        for (int jc = 0; jc < 4; ++jc) s += Sp[(jc * 16 + h) * 128 + tid];
        SfL[tid] = s;
    }
    __syncthreads();
    const int j = jt * 64 + (tid & 63);
    const int w = tid >> 6;
    float4 q = ((const float4*)Qn)[h * SL + j];
    BUILD_POWERS(q)
    float z;
    switch (w) {
        case 0:  z = z_part<0>(p0, p1, p2, p3, SfL); break;
        case 1:  z = z_part<1>(p0, p1, p2, p3, SfL); break;
        case 2:  z = z_part<2>(p0, p1, p2, p3, SfL); break;
        default: z = z_part<3>(p0, p1, p2, p3, SfL); break;
    }
    ZQ[tid] = z;
    __syncthreads();
    if (tid < 64) {
        float zt = (ZQ[tid] + ZQ[64 + tid]) + (ZQ[128 + tid] + ZQ[192 + tid]);
        float inv = 1.f / zt;
        float4 v = ((const float4*)V4f)[h * SL + jt * 64 + tid];
        ((float4*)Vz)[h * SL + jt * 64 + tid] =
            make_float4(v.x * inv, v.y * inv, v.z * inv, v.w * inv);
    }
    __syncthreads();
}

// P4: Mp[jc][h][f][d] partials, 512 workers (16 fc x 16 h x 2 jc).
template <int FC>
__device__ __forceinline__ void m_accum(int h, int jc, int tid,
        const float* __restrict__ Qn, const float* __restrict__ Vz,
        float acc[32])
{
    for (int u = 0; u < 8; ++u) {
        int j = jc * 2048 + u * 256 + tid;
        float4 q = ((const float4*)Qn)[h * SL + j];
        float4 v = ((const float4*)Vz)[h * SL + j];
        BUILD_POWERS(q)
        FOR_MONOMIALS({
            if (f >= FC * 8 && f < FC * 8 + 8) {
                const int fi = f - FC * 8;
                float m = (p0[a] * p1[b]) * (p2[c] * p3[d]);
                acc[fi*4+0] = fmaf(m, v.x, acc[fi*4+0]);
                acc[fi*4+1] = fmaf(m, v.y, acc[fi*4+1]);
                acc[fi*4+2] = fmaf(m, v.z, acc[fi*4+2]);
                acc[fi*4+3] = fmaf(m, v.w, acc[fi*4+3]);
            }
        })
    }
}

__device__ __forceinline__ void phase_mmat(int bid, int tid, float* lds,
    const float* __restrict__ Qn, const float* __restrict__ Vz,
    float* __restrict__ Mp)
{
    if (bid >= 512) return;
    const int fc = bid & 15, h = (bid >> 4) & 15, jc = bid >> 8;
    float acc[32];
    #pragma unroll
    for (int k = 0; k < 32; ++k) acc[k] = 0.f;
    switch (fc) {
        case 0:  m_accum<0 >(h, jc, tid, Qn, Vz, acc); break;
        case 1:  m_accum<1 >(h, jc, tid, Qn, Vz, acc); break;
        case 2:  m_accum<2 >(h, jc, tid, Qn, Vz, acc); break;
        case 3:  m_accum<3 >(h, jc, tid, Qn, Vz, acc); break;
        case 4:  m_accum<4 >(h, jc, tid, Qn, Vz, acc); break;
        case 5:  m_accum<5 >(h, jc, tid, Qn, Vz, acc); break;
        case 6:  m_accum<6 >(h, jc, tid, Qn, Vz, acc); break;
        case 7:  m_accum<7 >(h, jc, tid, Qn, Vz, acc); break;
        case 8:  m_accum<8 >(h, jc, tid, Qn, Vz, acc); break;
        case 9:  m_accum<9 >(h, jc, tid, Qn, Vz, acc); break;
        case 10: m_accum<10>(h, jc, tid, Qn, Vz, acc); break;
        case 11: m_accum<11>(h, jc, tid, Qn, Vz, acc); break;
        case 12: m_accum<12>(h, jc, tid, Qn, Vz, acc); break;
        case 13: m_accum<13>(h, jc, tid, Qn, Vz, acc); break;
        case 14: m_accum<14>(h, jc, tid, Qn, Vz, acc); break;
        default: m_accum<15>(h, jc, tid, Qn, Vz, acc); break;
    }
    #pragma unroll
    for (int off = 32; off; off >>= 1)
        #pragma unroll
        for (int k = 0; k < 32; ++k) acc[k] += __shfl_down(acc[k], off);
    float* red = lds;                          // [4][32]
    const int lane = tid & 63, wv = tid >> 6;
    if (lane == 0) {
        #pragma unroll
        for (int k = 0; k < 32; ++k) red[wv * 32 + k] = acc[k];
    }
    __syncthreads();
    if (tid < 32) {
        int fi = tid >> 2, dd = tid & 3;
        int f = fc * 8 + fi;
        if (f < NF) {
            float s = (red[tid] + red[32 + tid]) + (red[64 + tid] + red[96 + tid]);
            int A, B, C, D; f2abcd(f, A, B, C, D);
            s *= (invfact(A) * invfact(B)) * (invfact(C) * invfact(D));
            Mp[((jc * 16 + h) * 128 + f) * 4 + dd] = s;
        }
    }
    __syncthreads();
}

// P4b: fold 2 Mp partials -> dense Mf[(h*126+f)*4+dd]. Workers: bid < 32.
__device__ __forceinline__ void phase_fold(int bid, int tid,
    const float* __restrict__ Mp, float* __restrict__ Mf)
{
    if (bid >= 32) return;
    int ed = bid * 256 + tid;                  // 0..8191
    if (ed < 8064) {
        int h = ed / 504;                      // 504 = 126*4
        int r = ed - h * 504;
        int src = h * 512 + r;                 // padded stride 128*4
        Mf[ed] = Mp[src] + Mp[8192 + src];
    }
}

// P5: fused AO + output projection + residual. Workers: bid < 512
// (128 tiles of 32 pos x 4 c-blocks). LDS: dense M 31.5 KB + AOL 8.25 KB.
__device__ __forceinline__ void phase_out(int bid, int tid, float* lds,
    const float* __restrict__ Kn, const float* __restrict__ Mf,
    const float* __restrict__ Wo, const float* __restrict__ bo,
    const float* __restrict__ X, float* __restrict__ Y)
{
    if (bid >= 512) return;
    float4* ML4 = (float4*)lds;                // 2016 float4
    float*  AOL = lds + 8064;                  // [64][33]
    const int it = bid & 127, cb = bid >> 7;
    const int i0 = it * 32;
    const float4* Mf4 = (const float4*)Mf;
    #pragma unroll
    for (int w = 0; w < 8; ++w) {
        int e = tid + w * 256;
        if (e < 2016) ML4[e] = Mf4[e];
    }
    __syncthreads();
    #pragma unroll
    for (int r = 0; r < 2; ++r) {
        int p = tid + r * 256;
        int pos = p & 31, h = p >> 5;
        float4 k = ((const float4*)Kn)[h * SL + i0 + pos];
        BUILD_POWERS(k)
        const float4* Mh = ML4 + h * 126;
        float a0 = 0.f, a1 = 0.f, a2 = 0.f, a3 = 0.f;
        FOR_MONOMIALS({
            float m = (p0[a] * p1[b]) * (p2[c] * p3[d]);
            float4 mm = Mh[f];
            a0 = fmaf(m, mm.x, a0); a1 = fmaf(m, mm.y, a1);
            a2 = fmaf(m, mm.z, a2); a3 = fmaf(m, mm.w, a3);
        })
        AOL[(h * 4 + 0) * 33 + pos] = a0;
        AOL[(h * 4 + 1) * 33 + pos] = a1;
        AOL[(h * 4 + 2) * 33 + pos] = a2;
        AOL[(h * 4 + 3) * 33 + pos] = a3;
    }
    __syncthreads();
    const int pos = tid & 31, cg_ = tid >> 5;
    const int chb = cb * 64 + cg_ * 8;
    float acc[8];
    #pragma unroll
    for (int u = 0; u < 8; ++u) acc[u] = 0.f;
    #pragma unroll 4
    for (int ob = 0; ob < 16; ++ob) {
        float x0 = AOL[(ob * 4 + 0) * 33 + pos];
        float x1 = AOL[(ob * 4 + 1) * 33 + pos];
        float x2 = AOL[(ob * 4 + 2) * 33 + pos];
        float x3 = AOL[(ob * 4 + 3) * 33 + pos];
        #pragma unroll
        for (int u = 0; u < 8; ++u) {
            float4 w4 = ((const float4*)Wo)[(chb + u) * 16 + ob];
            acc[u] = fmaf(w4.x, x0, fmaf(w4.y, x1,
                     fmaf(w4.z, x2, fmaf(w4.w, x3, acc[u]))));
        }
    }
    #pragma unroll
    for (int u = 0; u < 8; ++u) {
        int ch = chb + u;
        Y[ch * SL + i0 + pos] = acc[u] + bo[ch] + X[ch * SL + i0 + pos];
    }
}

// ============================ kernels ======================================

__global__ __launch_bounds__(256, 4) void mega_kernel(
    const float* __restrict__ X,
    const float* __restrict__ Wq, const float* __restrict__ bq,
    const float* __restrict__ Wk, const float* __restrict__ bk,
    const float* __restrict__ Wv, const float* __restrict__ bv,
    const float* __restrict__ Wo, const float* __restrict__ bo,
    float* __restrict__ Y,
    float* __restrict__ Qn, float* __restrict__ Kn,
    float* __restrict__ V4f, float* __restrict__ Vz,
    float* __restrict__ Sp, float* __restrict__ Mp, float* __restrict__ Mf)
{
    __shared__ __align__(16) float lds[10176];     // 39.75 KB (4 blocks/CU)
    cg::grid_group g = cg::this_grid();
    const int bid = blockIdx.x, tid = threadIdx.x;
    phase_qkv(bid, tid, X, Wq, bq, Wk, bk, Wv, bv, Qn, Kn, V4f);
    g.sync();
    phase_ssum(bid, tid, lds, Kn, Sp);
    g.sync();
    phase_zvz(bid, tid, lds, Qn, Sp, V4f, Vz);
    g.sync();
    phase_mmat(bid, tid, lds, Qn, Vz, Mp);
    g.sync();
    phase_fold(bid, tid, Mp, Mf);
    g.sync();
    phase_out(bid, tid, lds, Kn, Mf, Wo, bo, X, Y);
}

// -------- fallback standalone kernels (same phase bodies) ------------------
__global__ __launch_bounds__(256) void k_qkv(
    const float* X, const float* Wq, const float* bq, const float* Wk,
    const float* bk, const float* Wv, const float* bv,
    float* Qn, float* Kn, float* V4f)
{ phase_qkv(blockIdx.x, threadIdx.x, X, Wq, bq, Wk, bk, Wv, bv, Qn, Kn, V4f); }

__global__ __launch_bounds__(256) void k_ssum(const float* Kn, float* Sp)
{ __shared__ float lds[32]; phase_ssum(blockIdx.x, threadIdx.x, lds, Kn, Sp); }

__global__ __launch_bounds__(256) void k_zvz(
    const float* Qn, const float* Sp, const float* V4f, float* Vz)
{ __shared__ float lds[384]; phase_zvz(blockIdx.x, threadIdx.x, lds, Qn, Sp, V4f, Vz); }

__global__ __launch_bounds__(256) void k_mmat(
    const float* Qn, const float* Vz, float* Mp)
{ __shared__ float lds[128]; phase_mmat(blockIdx.x, threadIdx.x, lds, Qn, Vz, Mp); }

__global__ __launch_bounds__(256) void k_fold(const float* Mp, float* Mf)
{ phase_fold(blockIdx.x, threadIdx.x, Mp, Mf); }

__global__ __launch_bounds__(256) void k_out(
    const float* Kn, const float* Mf, const float* Wo, const float* bo,
    const float* X, float* Y)
{
    __shared__ __align__(16) float lds[10176];
    phase_out(blockIdx.x, threadIdx.x, lds, Kn, Mf, Wo, bo, X, Y);
}

// ---------------------------------------------------------------------------
extern "C" void kernel_launch(void* const* d_in, const int* in_sizes, int n_in,
                              void* d_out, int out_size, void* d_ws, size_t ws_size,
                              hipStream_t stream)
{
    const float* X  = (const float*)d_in[0];
    const float* Wq = (const float*)d_in[1];
    const float* bq = (const float*)d_in[2];
    const float* Wk = (const float*)d_in[3];
    const float* bk = (const float*)d_in[4];
    const float* Wv = (const float*)d_in[5];
    const float* bv = (const float*)d_in[6];
    const float* Wo = (const float*)d_in[7];
    const float* bo = (const float*)d_in[8];
    float* Y = (float*)d_out;

    char* w = (char*)d_ws;
    float* Qn  = (float*)(w + (0 << 20));   // [16][SL][4]     1 MB
    float* Kn  = (float*)(w + (1 << 20));   // [16][SL][4]     1 MB
    float* V4f = (float*)(w + (2 << 20));   // [16][SL][4]     1 MB
    float* Vz  = (float*)(w + (3 << 20));   // [16][SL][4]     1 MB
    float* Sp  = (float*)(w + (4 << 20));                    // 32 KB
    float* Mp  = (float*)(w + (4 << 20) + (128 << 10));      // 64 KB
    float* Mf  = (float*)(w + (4 << 20) + (256 << 10));      // 32 KB

    int maxb = 0;
    hipError_t qe = hipOccupancyMaxActiveBlocksPerMultiprocessor(
        &maxb, mega_kernel, 256, 0);
    if (qe == hipSuccess && maxb >= 4) {
        void* args[] = { (void*)&X, (void*)&Wq, (void*)&bq, (void*)&Wk,
                         (void*)&bk, (void*)&Wv, (void*)&bv, (void*)&Wo,
                         (void*)&bo, (void*)&Y, (void*)&Qn, (void*)&Kn,
                         (void*)&V4f, (void*)&Vz, (void*)&Sp, (void*)&Mp,
                         (void*)&Mf };
        (void)hipLaunchCooperativeKernel((const void*)mega_kernel,
                                         dim3(1024), dim3(256), args, 0, stream);
    } else {
        k_qkv <<<768,  256, 0, stream>>>(X, Wq, bq, Wk, bk, Wv, bv, Qn, Kn, V4f);
        k_ssum<<<1024, 256, 0, stream>>>(Kn, Sp);
        k_zvz <<<1024, 256, 0, stream>>>(Qn, Sp, V4f, Vz);
        k_mmat<<<512,  256, 0, stream>>>(Qn, Vz, Mp);
        k_fold<<<32,   256, 0, stream>>>(Mp, Mf);
        k_out <<<512,  256, 0, stream>>>(Kn, Mf, Wo, bo, X, Y);
    }
}